// Round 6
// baseline (1448.591 us; speedup 1.0000x reference)
//
#include <hip/hip_runtime.h>
#include <type_traits>
#include <utility>

typedef _Float16 f16;
typedef f16 f16x4 __attribute__((ext_vector_type(4)));
typedef f16 f16x8 __attribute__((ext_vector_type(8)));
typedef float f32x4 __attribute__((ext_vector_type(4)));
typedef unsigned int u32;

#define MFMA __builtin_amdgcn_mfma_f32_16x16x32_f16
#define WGSCOPE __HIP_MEMORY_SCOPE_WORKGROUP

constexpr int Bsz = 256, T = 512, D = 128, H = 512, C = 128;
constexpr int ROWS = 16;          // batch rows per block (MFMA M)
constexpr int TPB  = 512;         // 8 waves
constexpr int LDH  = H + 8;       // b128 bank-uniform stride
constexpr int LDX  = D + 8;
constexpr int NTG  = H / 16;      // 32 n-tiles over H
constexpr int PKT  = 8;           // Whh k-tiles pinned in regs (kt 0..7)
constexpr int KTL  = 2;           // Whh k-tiles in LDS (kt 8..9)
constexpr int NSTR = 6;           // streamed k-tiles (kt 10..15)
constexpr int RING = 5;           // hbuf ring depth (skew budget = 4 steps)
constexpr int SLOT = ROWS * LDH;
constexpr size_t XSTRIDE = (size_t)16 * NTG * 256;  // xproj elems per timestep

// Per-wave rotated consumption schedule (compile-time).
// BASE spreads streamed tiles; wave V consumes kt = (BASE[j]+2V)&15, so its
// own tiles come first and each producer is needed at a different phase per
// wave -> cross-step pipeline (P < L). spin[j] = producer to wait on before
// first use (systematic: no missed-producer races).
struct Sched {
    int kt[16];
    int spin[16];
    int sidx[16];
    int skt[NSTR];
};
constexpr Sched make_sched(int V) {
    Sched s{};
    const int BASE[16] = {0, 10, 1, 11, 2, 3, 12, 4, 13, 5, 6, 14, 7, 15, 8, 9};
    bool seen[8] = {};
    seen[V] = true;
    int si = 0;
    for (int j = 0; j < 16; j++) {
        int kt = (BASE[j] + 2 * V) & 15;
        s.kt[j] = kt;
        int u = kt >> 1;
        s.spin[j] = seen[u] ? -1 : u;
        seen[u] = true;
        if (kt >= PKT + KTL) {
            s.sidx[j] = si;
            s.skt[si] = kt;
            si++;
        } else {
            s.sidx[j] = -1;
        }
    }
    return s;
}

// Pack fp32 [K][N] row-major -> fp16 MFMA-fragment order.
// k-slot map (BIJECTION, must match load_a): k = kt*32 + 8*(lane>>4) + e.
__global__ void pack_w(const float* __restrict__ W, int K, int N, f16* __restrict__ out) {
    int total = K * N;
    int NT = N / 16;
    for (int idx = blockIdx.x * blockDim.x + threadIdx.x; idx < total;
         idx += gridDim.x * blockDim.x) {
        int e    = idx & 7;
        int lane = (idx >> 3) & 63;
        int tile = idx >> 9;
        int kt = tile / NT, nt = tile % NT;
        int k = kt * 32 + 8 * (lane >> 4) + e;
        int n = nt * 16 + (lane & 15);
        out[idx] = (f16)W[(size_t)k * N + n];
    }
}

__device__ __forceinline__ f16x8 load_a(const f16* base, int ld, int kt, int l15, int l4) {
    return *(const f16x8*)(base + l15 * ld + kt * 32 + 8 * l4);
}

// tanh(v) = 1 - 2/(e^{2v}+1); exp->inf => rcp->0 => +/-1 (no clamp needed).
__device__ __forceinline__ float fast_tanh(float v) {
    float e = __expf(2.f * v);
    return 1.f - __fdividef(2.f, e + 1.f);
}

// xproj = x_t @ Whx + bh in MFMA C-fragment order (f32 or f16). Runs on all CUs.
template <typename OT>
__global__ __launch_bounds__(TPB, 2) void xproj_k(
    const float* __restrict__ x, const f16* __restrict__ wpack,
    const float* __restrict__ bh, OT* __restrict__ xp) {
    const f16* Whx_p = wpack;
    __shared__ __align__(16) f16 xb[2][ROWS][LDX];
    const int tid = threadIdx.x, lane = tid & 63, w = tid >> 6;
    const int l15 = lane & 15, l4 = lane >> 4;
    const int bt = blockIdx.x;
    const int t0 = blockIdx.y * 16;
    const int b0 = bt * ROWS;
    const int xrow = tid >> 5, xd0 = (tid & 31) * 4;
    const int ntg0 = w * 4;

    float bh4[4];
#pragma unroll
    for (int nt = 0; nt < 4; nt++) bh4[nt] = bh[(ntg0 + nt) * 16 + l15];
    {
        float4 v = *(const float4*)&x[((size_t)(b0 + xrow) * T + t0) * D + xd0];
        f16x4 h4 = {(f16)v.x, (f16)v.y, (f16)v.z, (f16)v.w};
        *(f16x4*)&xb[0][xrow][xd0] = h4;
    }
    __syncthreads();

    int p = 0;
    for (int tt = 0; tt < 16; tt++) {
        int t = t0 + tt;
        float4 xv;
        const bool havex = (tt + 1 < 16);
        if (havex)
            xv = *(const float4*)&x[((size_t)(b0 + xrow) * T + (t + 1)) * D + xd0];
        f32x4 acc[4];
#pragma unroll
        for (int nt = 0; nt < 4; nt++)
            acc[nt] = (f32x4){bh4[nt], bh4[nt], bh4[nt], bh4[nt]};
#pragma unroll
        for (int kt = 0; kt < D / 32; kt++) {
            f16x8 a = load_a(&xb[p][0][0], LDX, kt, l15, l4);
            const f16* btp = Whx_p + (((size_t)kt * NTG + ntg0) * 64 + lane) * 8;
#pragma unroll
            for (int nt = 0; nt < 4; nt++) {
                f16x8 b = *(const f16x8*)(btp + (size_t)nt * 512);
                acc[nt] = MFMA(a, b, acc[nt], 0, 0, 0);
            }
        }
        if (havex) {
            f16x4 h4 = {(f16)xv.x, (f16)xv.y, (f16)xv.z, (f16)xv.w};
            *(f16x4*)&xb[p ^ 1][xrow][xd0] = h4;
        }
        OT* op = xp + (((size_t)t * 16 + bt) * NTG + ntg0) * 256 + (size_t)lane * 4;
#pragma unroll
        for (int nt = 0; nt < 4; nt++) {
            if constexpr (std::is_same_v<OT, float>) {
                *(f32x4*)(op + (size_t)nt * 256) = acc[nt];
            } else {
                f16x4 v = {(f16)acc[nt][0], (f16)acc[nt][1], (f16)acc[nt][2],
                           (f16)acc[nt][3]};
                *(f16x4*)(op + (size_t)nt * 256) = v;
            }
        }
        __syncthreads();
        p ^= 1;
    }
}

// XP=1: f32 xproj. XP=2: f16 xproj. XP=0: in-loop Whx fallback (barrier-synced).
template <int XP>
__global__ __launch_bounds__(TPB, 2) void rnn_main(
    const float* __restrict__ x, const f16* __restrict__ wpack,
    const void* __restrict__ xproj, const float* __restrict__ bh,
    const float* __restrict__ bp, float* __restrict__ out) {
    const f16* Whx_p = wpack;
    const f16* Whh_p = wpack + D * H;
    const f16* Wph_p = wpack + D * H + H * H;

    __shared__ __align__(16) f16 hbuf[RING][ROWS][LDH];        // 83.2 KB ring
    __shared__ __align__(16) f16 whh_lds[KTL * NTG * 64 * 8];  // 64 KB, kt 8..9
    __shared__ int pflag[8];   // pflag[v]=s: v's chunk of h_s readable
    __shared__ int cflag[8];   // cflag[v]=s: v finished all reads of h_s
    __shared__ __align__(16) f16 xbuf[(XP == 0) ? 2 : 1][(XP == 0) ? ROWS : 1]
                                     [(XP == 0) ? LDX : 8];

    const int tid = threadIdx.x, lane = tid & 63, w = tid >> 6;
    const int l15 = lane & 15, l4 = lane >> 4;
    const int b0 = blockIdx.x * ROWS;
    const int xrow = tid >> 5, xd0 = (tid & 31) * 4;

    // Pinned Whh kt 0..7 (128 regs, AGPR-resident).
    f16x8 wreg[PKT][4];
#pragma unroll
    for (int kt = 0; kt < PKT; kt++)
#pragma unroll
        for (int nt = 0; nt < 4; nt++)
            wreg[kt][nt] =
                *(const f16x8*)(Whh_p + (((size_t)kt * NTG + w * 4 + nt) * 64 + lane) * 8);

    // Stage Whh kt 8..9 into LDS.
    {
        const f16* src = Whh_p + (size_t)PKT * NTG * 512;
        for (int i = tid; i < KTL * NTG * 64; i += TPB)
            *(f16x8*)&whh_lds[(size_t)i * 8] = *(const f16x8*)(src + (size_t)i * 8);
    }
    for (int i = tid; i < SLOT; i += TPB) (&hbuf[0][0][0])[i] = (f16)0.f;
    if (tid < 8) { pflag[tid] = 0; cflag[tid] = -1000; }

    float bh4[4];
    const float* xpf = nullptr;
    const f16* xph = nullptr;
    if constexpr (XP == 1) {
        xpf = (const float*)xproj + (((size_t)blockIdx.x * NTG + w * 4) * 64 + lane) * 4;
    } else if constexpr (XP == 2) {
        xph = (const f16*)xproj + (((size_t)blockIdx.x * NTG + w * 4) * 64 + lane) * 4;
    } else {
#pragma unroll
        for (int nt = 0; nt < 4; nt++) bh4[nt] = bh[(w * 4 + nt) * 16 + l15];
        float4 v = *(const float4*)&x[((size_t)(b0 + xrow) * T + 0) * D + xd0];
        f16x4 h4 = {(f16)v.x, (f16)v.y, (f16)v.z, (f16)v.w};
        *(f16x4*)&xbuf[0][xrow][xd0] = h4;
    }
    __syncthreads();  // one-time: init visible

    f16* const hbase = &hbuf[0][0][0];

    // ---------------- per-wave-variant main loop ----------------
    auto run = [&](auto vc) {
        constexpr int V = decltype(vc)::value;
        constexpr Sched S = make_sched(V);
        constexpr int ntg0 = V * 4;

        // vector poll: bit u of result = (flag[u] >= tgt)
        auto pollp = [&](int tgt) -> u32 {
            int f = __hip_atomic_load(&pflag[lane & 7], __ATOMIC_ACQUIRE, WGSCOPE);
            return (u32)__ballot(f >= tgt) & 0xffu;
        };
        auto pollc = [&](int tgt) -> u32 {
            int f = __hip_atomic_load(&cflag[lane & 7], __ATOMIC_ACQUIRE, WGSCOPE);
            return (u32)__ballot(f >= tgt) & 0xffu;
        };

        // Prologue: preload first two streamed tiles.
        f16x8 sb0[4], sb1[4];
        {
            const f16* wb0 = Whh_p + ((size_t)ntg0 * 64 + lane) * 8;
#pragma unroll
            for (int nt = 0; nt < 4; nt++)
                sb0[nt] = *(const f16x8*)(wb0 + ((size_t)S.skt[0] * NTG + nt) * 512);
#pragma unroll
            for (int nt = 0; nt < 4; nt++)
                sb1[nt] = *(const f16x8*)(wb0 + ((size_t)S.skt[1] * NTG + nt) * 512);
        }

        int sR = 0, sW = 1;
#pragma unroll 1
        for (int t = 0; t < T; t++) {
            const f16* hb = hbase + sR * SLOT;
            f16* hw = hbase + sW * SLOT;

            uintptr_t whu = (uintptr_t)Whh_p;
            asm volatile("" : "+s"(whu));  // defeat LICM on invariant weight loads
            const f16* wbase = (const f16*)whu + ((size_t)ntg0 * 64 + lane) * 8;
            u32 zo = 0;
            asm volatile("" : "+v"(zo));
            const f16x8* wlds = (const f16x8*)whh_lds + zo;

            // this step's xproj fragments (consumed pre-tanh)
            f32x4 xr32[4];
            f16x4 xr16[4];
            if constexpr (XP == 1) {
                const float* xq = xpf + (size_t)t * XSTRIDE;
#pragma unroll
                for (int nt = 0; nt < 4; nt++)
                    xr32[nt] = *(const f32x4*)(xq + (size_t)nt * 256);
            } else if constexpr (XP == 2) {
                const f16* xq = xph + (size_t)t * XSTRIDE;
#pragma unroll
                for (int nt = 0; nt < 4; nt++)
                    xr16[nt] = *(const f16x4*)(xq + (size_t)nt * 256);
            }

            f32x4 acc[4];
            if constexpr (XP == 0) {
#pragma unroll
                for (int nt = 0; nt < 4; nt++)
                    acc[nt] = (f32x4){bh4[nt], bh4[nt], bh4[nt], bh4[nt]};
            } else {
#pragma unroll
                for (int nt = 0; nt < 4; nt++) acc[nt] = (f32x4){0.f, 0.f, 0.f, 0.f};
            }

            if constexpr (XP == 0) {
                float4 xv;
                const bool havex = (t + 1 < T);
                if (havex)
                    xv = *(const float4*)&x[((size_t)(b0 + xrow) * T + (t + 1)) * D + xd0];
                uintptr_t wxu = (uintptr_t)Whx_p;
                asm volatile("" : "+s"(wxu));
                const f16* wxs = (const f16*)wxu;
#pragma unroll
                for (int kt = 0; kt < D / 32; kt++) {
                    f16x8 a = load_a(&xbuf[t & 1][0][0], LDX, kt, l15, l4);
                    const f16* bt = wxs + (((size_t)kt * NTG + ntg0) * 64 + lane) * 8;
#pragma unroll
                    for (int nt = 0; nt < 4; nt++) {
                        f16x8 b = *(const f16x8*)(bt + (size_t)nt * 512);
                        acc[nt] = MFMA(a, b, acc[nt], 0, 0, 0);
                    }
                }
                if (havex) {
                    f16x4 h4 = {(f16)xv.x, (f16)xv.y, (f16)xv.z, (f16)xv.w};
                    *(f16x4*)&xbuf[(t & 1) ^ 1][xrow][xd0] = h4;
                }
            }

            u32 kmask = 1u << V;  // producers confirmed for step t

            // one tile position: spin (first use) -> A-read -> 4 MFMAs [-> LS]
            auto pos = [&](auto jc) {
                constexpr int j = decltype(jc)::value;
                if constexpr (XP != 0 && S.spin[j] >= 0) {
                    constexpr int u = S.spin[j];
                    while (!((kmask >> u) & 1u)) kmask = pollp(t);
                }
                constexpr int kt = S.kt[j];
                f16x8 a = load_a(hb, LDH, kt, l15, l4);
                if constexpr (kt < PKT) {
#pragma unroll
                    for (int nt = 0; nt < 4; nt++)
                        acc[nt] = MFMA(a, wreg[kt][nt], acc[nt], 0, 0, 0);
                } else if constexpr (kt < PKT + KTL) {
#pragma unroll
                    for (int nt = 0; nt < 4; nt++)
                        acc[nt] = MFMA(
                            a, wlds[((size_t)(kt - PKT) * NTG + ntg0 + nt) * 64 + lane],
                            acc[nt], 0, 0, 0);
                } else {
                    constexpr int i = S.sidx[j];
                    constexpr int nk = S.skt[(i + 2) % NSTR];
                    if constexpr ((i & 1) == 0) {
#pragma unroll
                        for (int nt = 0; nt < 4; nt++)
                            acc[nt] = MFMA(a, sb0[nt], acc[nt], 0, 0, 0);
#pragma unroll
                        for (int nt = 0; nt < 4; nt++)
                            sb0[nt] = *(const f16x8*)(wbase + ((size_t)nk * NTG + nt) * 512);
                    } else {
#pragma unroll
                        for (int nt = 0; nt < 4; nt++)
                            acc[nt] = MFMA(a, sb1[nt], acc[nt], 0, 0, 0);
#pragma unroll
                        for (int nt = 0; nt < 4; nt++)
                            sb1[nt] = *(const f16x8*)(wbase + ((size_t)nk * NTG + nt) * 512);
                    }
                }
            };
#define POS(J) pos(std::integral_constant<int, J>{})
            POS(0);  POS(1);  POS(2);  POS(3);
            POS(4);  POS(5);  POS(6);  POS(7);
            POS(8);  POS(9);  POS(10); POS(11);
            POS(12); POS(13); POS(14); POS(15);
#undef POS

            if constexpr (XP != 0) {
                // all reads of h_t issued & (release) retired
                if (lane == 0)
                    __hip_atomic_store(&cflag[V], t, __ATOMIC_RELEASE, WGSCOPE);
                // back-pressure: slot sW previously held h_{t-4}; its readers
                // (bodies t-4) must be done before we overwrite.
                int tgt = t - (RING - 1);
                while (pollc(tgt) != 0xffu) {
                }
            }

            // h_new = tanh(acc [+ xproj]); C/D: col=lane&15, row=4*(lane>>4)+r
#pragma unroll
            for (int nt = 0; nt < 4; nt++)
#pragma unroll
                for (int r = 0; r < 4; r++) {
                    float v = acc[nt][r];
                    if constexpr (XP == 1) v += xr32[nt][r];
                    else if constexpr (XP == 2) v += (float)xr16[nt][r];
                    float th = fast_tanh(v);
                    hw[(l4 * 4 + r) * LDH + (ntg0 + nt) * 16 + l15] = (f16)th;
                }
            if constexpr (XP != 0) {
                if (lane == 0)
                    __hip_atomic_store(&pflag[V], t + 1, __ATOMIC_RELEASE, WGSCOPE);
            } else {
                __syncthreads();
            }

            sR = (sR + 1 == RING) ? 0 : sR + 1;
            sW = (sW + 1 == RING) ? 0 : sW + 1;
        }
    };

    switch (w) {
        case 0: run(std::integral_constant<int, 0>{}); break;
        case 1: run(std::integral_constant<int, 1>{}); break;
        case 2: run(std::integral_constant<int, 2>{}); break;
        case 3: run(std::integral_constant<int, 3>{}); break;
        case 4: run(std::integral_constant<int, 4>{}); break;
        case 5: run(std::integral_constant<int, 5>{}); break;
        case 6: run(std::integral_constant<int, 6>{}); break;
        default: run(std::integral_constant<int, 7>{}); break;
    }

    // wait for all waves' h_T, then out = h_T @ Wph + bp
    if constexpr (XP != 0) {
        for (;;) {
            int f = __hip_atomic_load(&pflag[lane & 7], __ATOMIC_ACQUIRE, WGSCOPE);
            if (((u32)__ballot(f >= T) & 0xffu) == 0xffu) break;
        }
    } else {
        __syncthreads();
    }
    {
        const f16* hT = hbase + (T % RING) * SLOT;
        float bpv = bp[w * 16 + l15];
        f32x4 acc = {bpv, bpv, bpv, bpv};
#pragma unroll 4
        for (int kt = 0; kt < H / 32; kt++) {
            f16x8 a = load_a(hT, LDH, kt, l15, l4);
            f16x8 b = *(const f16x8*)(Wph_p + (((size_t)kt * (C / 16) + w) * 64 + lane) * 8);
            acc = MFMA(a, b, acc, 0, 0, 0);
        }
#pragma unroll
        for (int r = 0; r < 4; r++)
            out[(size_t)(b0 + l4 * 4 + r) * C + w * 16 + l15] = acc[r];
    }
}

extern "C" void kernel_launch(void* const* d_in, const int* in_sizes, int n_in,
                              void* d_out, int out_size, void* d_ws, size_t ws_size,
                              hipStream_t stream) {
    const float* x   = (const float*)d_in[0];
    const float* Whx = (const float*)d_in[1];
    const float* Whh = (const float*)d_in[2];
    const float* Wph = (const float*)d_in[3];
    const float* bh  = (const float*)d_in[4];
    const float* bp  = (const float*)d_in[5];

    f16* wp = (f16*)d_ws; // 768 KB packed fp16 weights
    pack_w<<<dim3(128), 256, 0, stream>>>(Whx, D, H, wp);
    pack_w<<<dim3(512), 256, 0, stream>>>(Whh, H, H, wp + D * H);
    pack_w<<<dim3(128), 256, 0, stream>>>(Wph, H, C, wp + D * H + H * H);

    const size_t wbytes = (size_t)(D * H + H * H + H * C) * sizeof(f16); // 768 KB
    const size_t xpel   = (size_t)T * 16 * NTG * 256;                    // 67.1M elems

    if (ws_size >= wbytes + xpel * sizeof(float)) {        // 257 MB: f32 xproj
        float* xpb = (float*)((char*)d_ws + wbytes);
        xproj_k<float><<<dim3(16, T / 16), TPB, 0, stream>>>(x, wp, bh, xpb);
        rnn_main<1><<<dim3(Bsz / ROWS), TPB, 0, stream>>>(x, wp, xpb, bh, bp,
                                                          (float*)d_out);
    } else if (ws_size >= wbytes + xpel * sizeof(f16)) {   // 129 MB: f16 xproj
        f16* xpb = (f16*)((char*)d_ws + wbytes);
        xproj_k<f16><<<dim3(16, T / 16), TPB, 0, stream>>>(x, wp, bh, xpb);
        rnn_main<2><<<dim3(Bsz / ROWS), TPB, 0, stream>>>(x, wp, xpb, bh, bp,
                                                          (float*)d_out);
    } else {                                               // fallback: in-loop Whx
        rnn_main<0><<<dim3(Bsz / ROWS), TPB, 0, stream>>>(x, wp, nullptr, bh, bp,
                                                          (float*)d_out);
    }
}